// Round 6
// baseline (313.549 us; speedup 1.0000x reference)
//
#include <hip/hip_runtime.h>
#include <hip/hip_bf16.h>
#include <math.h>

// Problem constants
#define BATCH 1024
#define NREAL 784
#define NPAD  896      // 7*128 zero-padded graph dim
#define C1D   32
#define C2D   32
#define HDIM  512
#define NCLS  10
#define KFC   25088    // 784*32

#define KS_G1 4        // split-K G1: 7 iters/slice
#define KS_FC 14       // split-K fc1: 56 iters/slice

// ---------------------------------------------------------------------------
// Fragment-major storage: matrix M[R][K] (R mult 16, K mult 32) stored as
// chunks of 1024 B: chunk = (row>>4)*(K/32) + (k>>5); within chunk, element
// (row,k) at elem offset ((k>>3)&3)*128 + (row&15)*8 + (k&7).  Lane L of a
// wave reads its 16x16x32 MFMA A/B fragment as the 16 B at L*16 — so the
// GEMM needs only coalesced global_load_dwordx4, no LDS, no barriers.
// ---------------------------------------------------------------------------

using bf16x8  = __attribute__((ext_vector_type(8))) __bf16;
using floatx4 = __attribute__((ext_vector_type(4))) float;

__device__ __forceinline__ float elu_f(float t) {
    return t > 0.f ? t : (__expf(t) - 1.f);
}

__device__ __forceinline__ bf16x8 ld8(const __hip_bfloat16* p) {
    return *(const bf16x8*)p;
}

__device__ __forceinline__ void mfma16(const bf16x8 a[4], const bf16x8 b[4],
                                       floatx4 acc[4][4]) {
    #pragma unroll
    for (int mi = 0; mi < 4; mi++)
        #pragma unroll
        for (int nj = 0; nj < 4; nj++)
            acc[mi][nj] = __builtin_amdgcn_mfma_f32_16x16x32_bf16(a[mi], b[nj], acc[mi][nj], 0, 0, 0);
}

// ---------------------------------------------------------------------------
// Fragment-direct BT-GEMM: C[row][col] = sum_k A[row][k]*B[col][k], both in
// frag layout. One wave per 64x64 output tile; 4 independent waves per block
// (no barriers, no LDS). 2-deep named prefetch sets; any kIters >= 1.
// wid = blockIdx.x*4+wave; row-tile64 = wid % mt, col-tile64 = wid / mt
// (consecutive wids share the B col-tile -> L1/L2 reuse).
// MODE 0/2: fp32 store outF[z*ss + row*ldc + col]            (G1, G4)
// MODE 1:   elu(acc+bias[col&31]) -> bf16, stored in h2f FRAG layout
//           (rows b, k = n*32+c, kc=784), masked to n<784     (G3)
// ---------------------------------------------------------------------------
template<int MODE>
__launch_bounds__(256)
__global__ void gemm_fd(const __hip_bfloat16* __restrict__ A,
                        const __hip_bfloat16* __restrict__ Bm,
                        int kcA, int kcB,   // K/32 chunk counts per row-tile
                        int mt,             // row-tile64 count
                        int kIters, int kPerZ, size_t sliceStride,
                        float* __restrict__ outF, int ldc,
                        __hip_bfloat16* __restrict__ outH,
                        const float* __restrict__ bias)
{
    const int lane = threadIdx.x & 63;
    const int wave = threadIdx.x >> 6;
    const int wid  = blockIdx.x * 4 + wave;
    const int row  = wid % mt;
    const int col  = wid / mt;
    const int kB0  = blockIdx.y * kPerZ;

    const __hip_bfloat16* aB = A  + ((size_t)(row * 4) * kcA + kB0) * 512 + lane * 8;
    const __hip_bfloat16* bB = Bm + ((size_t)(col * 4) * kcB + kB0) * 512 + lane * 8;

    floatx4 acc[4][4];
    const floatx4 zero4 = {0.f, 0.f, 0.f, 0.f};
    #pragma unroll
    for (int i = 0; i < 4; i++)
        #pragma unroll
        for (int j = 0; j < 4; j++) acc[i][j] = zero4;

    bf16x8 a0[4], b0[4], a1[4], b1[4];

    #pragma unroll
    for (int mi = 0; mi < 4; mi++) {
        a0[mi] = ld8(aB + (size_t)mi * kcA * 512);
        b0[mi] = ld8(bB + (size_t)mi * kcB * 512);
    }
    if (kIters > 1) {
        #pragma unroll
        for (int mi = 0; mi < 4; mi++) {
            a1[mi] = ld8(aB + (size_t)mi * kcA * 512 + 512);
            b1[mi] = ld8(bB + (size_t)mi * kcB * 512 + 512);
        }
    }

    for (int kt = 0; kt + 1 < kIters; kt += 2) {
        mfma16(a0, b0, acc);
        if (kt + 2 < kIters) {
            #pragma unroll
            for (int mi = 0; mi < 4; mi++) {
                a0[mi] = ld8(aB + (size_t)mi * kcA * 512 + (size_t)(kt + 2) * 512);
                b0[mi] = ld8(bB + (size_t)mi * kcB * 512 + (size_t)(kt + 2) * 512);
            }
        }
        mfma16(a1, b1, acc);
        if (kt + 3 < kIters) {
            #pragma unroll
            for (int mi = 0; mi < 4; mi++) {
                a1[mi] = ld8(aB + (size_t)mi * kcA * 512 + (size_t)(kt + 3) * 512);
                b1[mi] = ld8(bB + (size_t)mi * kcB * 512 + (size_t)(kt + 3) * 512);
            }
        }
    }
    if (kIters & 1) mfma16(a0, b0, acc);   // odd tail lives in set 0

    // epilogue: C/D layout col=lane&15, row=(lane>>4)*4+reg  [verified m89/m91]
    const int m0 = row * 64, n0 = col * 64;
    #pragma unroll
    for (int mi = 0; mi < 4; mi++) {
        #pragma unroll
        for (int nj = 0; nj < 4; nj++) {
            #pragma unroll
            for (int r = 0; r < 4; r++) {
                const int orow = m0 + mi * 16 + (lane >> 4) * 4 + r;
                const int ocol = n0 + nj * 16 + (lane & 15);
                const float v = acc[mi][nj][r];
                if (MODE == 1) {
                    if (orow < NREAL) {   // orow = graph node n
                        const int b = ocol >> 5, c = ocol & 31;
                        const float t = elu_f(v + bias[c]);
                        // h2f frag: rows b, k = n*32+c, kc = 784 (kb == n)
                        const size_t ad = ((size_t)(b >> 4) * 784 + orow) * 512
                                        + (c >> 3) * 128 + (b & 15) * 8 + (c & 7);
                        outH[ad] = __float2bfloat16(t);
                    }
                } else {
                    outF[(size_t)blockIdx.y * sliceStride + (size_t)orow * ldc + ocol] = v;
                }
            }
        }
    }
}

// ---------------------------------------------------------------------------
// prepXA: x [1024][784] f32 -> Xf frag (1024x896, kc=28), zero k-pad
//         a [784][784]  f32 -> Af frag (896x896, kc=28), zero row/k-pad
// Thread = chunk*64+L -> fully coalesced 16 B frag stores.
// ---------------------------------------------------------------------------
__global__ void prepXA(const float* __restrict__ x, const float* __restrict__ a,
                       __hip_bfloat16* __restrict__ Xf, __hip_bfloat16* __restrict__ Af)
{
    const int XC = (BATCH / 16) * (NPAD / 32);   // 1792 chunks
    const int AC = (NPAD / 16) * (NPAD / 32);    // 1568 chunks
    int t = blockIdx.x * 256 + threadIdx.x;      // grid exact: (XC+AC)*64
    const float* src;
    __hip_bfloat16* dst;
    int chunk, L, rowsValid;
    if (t < XC * 64) {
        chunk = t >> 6; L = t & 63; src = x; dst = Xf; rowsValid = BATCH;
    } else {
        t -= XC * 64; chunk = t >> 6; L = t & 63; src = a; dst = Af; rowsValid = NREAL;
    }
    const int row = (chunk / 28) * 16 + (L & 15);
    const int k0  = ((chunk % 28) * 4 + (L >> 4)) * 8;
    __hip_bfloat16 o[8];
    if (k0 < NREAL && row < rowsValid) {
        const float4* p = (const float4*)(src + (size_t)row * NREAL + k0);
        const float4 lo = p[0], hi = p[1];
        o[0] = __float2bfloat16(lo.x); o[1] = __float2bfloat16(lo.y);
        o[2] = __float2bfloat16(lo.z); o[3] = __float2bfloat16(lo.w);
        o[4] = __float2bfloat16(hi.x); o[5] = __float2bfloat16(hi.y);
        o[6] = __float2bfloat16(hi.z); o[7] = __float2bfloat16(hi.w);
    } else {
        #pragma unroll
        for (int j = 0; j < 8; j++) o[j] = __float2bfloat16(0.f);
    }
    *(int4*)(dst + (size_t)chunk * 512 + L * 8) = *(const int4*)o;
}

// ---------------------------------------------------------------------------
// prepW: wf1 [25088][512] f32 -> Wf frag (rows h=512, k=n*32+c, kc=784).
// t = ku*512 + h: per fixed j, 512 consecutive h -> fully coalesced reads.
// ---------------------------------------------------------------------------
__global__ void prepW(const float* __restrict__ wf1, __hip_bfloat16* __restrict__ Wf)
{
    const int t = blockIdx.x * 256 + threadIdx.x;   // exact: 3136*512
    const int h  = t & 511;
    const int ku = t >> 9;          // 0..3135
    const int n  = ku >> 2;
    const int g  = ku & 3;          // k-octet within the 32-k block
    const int c0 = g * 8;
    __hip_bfloat16 o[8];
    #pragma unroll
    for (int j = 0; j < 8; j++)
        o[j] = __float2bfloat16(wf1[((size_t)(n * 32 + c0 + j)) * HDIM + h]);
    const size_t ad = ((size_t)(h >> 4) * 784 + n) * 512 + g * 128 + (h & 15) * 8;
    *(int4*)(Wf + ad) = *(const int4*)o;
}

// ---------------------------------------------------------------------------
// Layer-1 fused pointwise: reduce KS_G1 Y partials, then
// Tt[(b*32+c)][m] = sum_c' elu(Y[b][m]*w1[c']+b1[c'])*W2[c'][c],
// stored in FRAG layout (rows b*32+c, k=m, kc=28).
// ---------------------------------------------------------------------------
__global__ void layer1_fuse(const float* __restrict__ Ypart,
                            const float* __restrict__ w1, const float* __restrict__ b1,
                            const float* __restrict__ w2,
                            __hip_bfloat16* __restrict__ Tt)
{
    __shared__ __align__(16) float sW2[C1D * C2D];
    __shared__ float sw1[C1D], sb1[C1D];
    const int tid = threadIdx.x;                 // 128 threads
    for (int i = tid; i < C1D * C2D; i += 128) sW2[i] = w2[i];
    if (tid < C1D) { sw1[tid] = w1[tid]; sb1[tid] = b1[tid]; }
    __syncthreads();

    const int m = blockIdx.x * 128 + tid;        // 0..895
    const int b = blockIdx.y;
    float y = 0.f;
    #pragma unroll
    for (int z = 0; z < KS_G1; z++)
        y += Ypart[(size_t)z * (BATCH * NPAD) + (size_t)b * NPAD + m];

    float h[C1D];
    #pragma unroll
    for (int c1 = 0; c1 < C1D; c1++) h[c1] = elu_f(y * sw1[c1] + sb1[c1]);

    float4 t4[8];
    #pragma unroll
    for (int q = 0; q < 8; q++) t4[q] = make_float4(0.f, 0.f, 0.f, 0.f);
    #pragma unroll
    for (int c1 = 0; c1 < C1D; c1++) {
        const float hv = h[c1];
        const float4* row = (const float4*)(sW2 + c1 * C2D);
        #pragma unroll
        for (int q = 0; q < 8; q++) {
            const float4 w = row[q];
            t4[q].x += hv * w.x; t4[q].y += hv * w.y;
            t4[q].z += hv * w.z; t4[q].w += hv * w.w;
        }
    }
    const float* tf = (const float*)t4;
    // frag store: row=b*32+c, k=m
    const size_t inner = (size_t)((m >> 3) & 3) * 128 + (m & 7);
    #pragma unroll
    for (int c = 0; c < C2D; c++) {
        const size_t ad = ((size_t)(b * 2 + (c >> 4)) * 28 + (m >> 5)) * 512
                        + inner + (c & 15) * 8;
        Tt[ad] = __float2bfloat16(tf[c]);
    }
}

// ---------------------------------------------------------------------------
// fc1 reduce (split-K partials) + relu + fc2 + softmax, fused.
// ---------------------------------------------------------------------------
__global__ void fc2_softmax(const float* __restrict__ part, const float* __restrict__ bf1,
                            const float* __restrict__ wf2, const float* __restrict__ bf2,
                            float* __restrict__ out)
{
    __shared__ float sW[HDIM * NCLS];
    __shared__ float sb[NCLS];
    const int tid = threadIdx.x;                 // 256
    for (int i = tid; i < HDIM * NCLS; i += 256) sW[i] = wf2[i];
    if (tid < NCLS) sb[tid] = bf2[tid];
    __syncthreads();

    const int lane = tid & 63, wave = tid >> 6;
    const int b = blockIdx.x * 4 + wave;

    float acc[NCLS];
    #pragma unroll
    for (int c = 0; c < NCLS; c++) acc[c] = 0.f;
    #pragma unroll
    for (int q = 0; q < 8; q++) {
        const int h = q * 64 + lane;
        float hv = bf1[h];
        #pragma unroll
        for (int z = 0; z < KS_FC; z++)
            hv += part[(size_t)z * (BATCH * HDIM) + (size_t)b * HDIM + h];
        hv = hv > 0.f ? hv : 0.f;
        #pragma unroll
        for (int c = 0; c < NCLS; c++) acc[c] += hv * sW[h * NCLS + c];
    }
    #pragma unroll
    for (int c = 0; c < NCLS; c++) {
        #pragma unroll
        for (int off = 32; off >= 1; off >>= 1) acc[c] += __shfl_down(acc[c], off);
    }
    if (lane == 0) {
        float mx = -1e30f;
        #pragma unroll
        for (int c = 0; c < NCLS; c++) { acc[c] += sb[c]; mx = fmaxf(mx, acc[c]); }
        float e[NCLS], s = 0.f;
        #pragma unroll
        for (int c = 0; c < NCLS; c++) { e[c] = __expf(acc[c] - mx); s += e[c]; }
        const float inv = 1.f / s;
        #pragma unroll
        for (int c = 0; c < NCLS; c++) out[(size_t)b * NCLS + c] = e[c] * inv;
    }
}

// ---------------------------------------------------------------------------
// Workspace (same offsets as r5; all frag buffers have identical byte sizes)
//   h2f   [0,          51380224)  bf16 frag 1024 x kc784
//     Ypart [0, 14680064) f32 4x1024x896 — overlay, dead before G3
//   Tt    [51380224,  110100480)  bf16 frag 32768 x kc28  (dead after G3)
//     Wt   [51380224, 77070336)   bf16 frag 512 x kc784 — overlay after G3
//     part [77070336, 106430464)  f32 14x1024x512 — overlay after G3
//   Abf   [110100480, 111706112)  bf16 frag 896 x kc28
//   Xbf   [111706112, 113541120)  bf16 frag 1024 x kc28
// ---------------------------------------------------------------------------
extern "C" void kernel_launch(void* const* d_in, const int* in_sizes, int n_in,
                              void* d_out, int out_size, void* d_ws, size_t ws_size,
                              hipStream_t stream)
{
    const float* x   = (const float*)d_in[0];
    const float* a   = (const float*)d_in[1];
    const float* w1  = (const float*)d_in[2];
    const float* b1  = (const float*)d_in[3];
    const float* w2  = (const float*)d_in[4];
    const float* b2  = (const float*)d_in[5];
    const float* wf1 = (const float*)d_in[6];
    const float* bf1 = (const float*)d_in[7];
    const float* wf2 = (const float*)d_in[8];
    const float* bf2 = (const float*)d_in[9];
    float* out = (float*)d_out;

    char* ws = (char*)d_ws;
    __hip_bfloat16* h2f  = (__hip_bfloat16*)(ws + 0);
    float*          Ypart= (float*)(ws + 0);                  // overlay (pre-G3)
    __hip_bfloat16* Tt   = (__hip_bfloat16*)(ws + 51380224);
    __hip_bfloat16* Wt   = (__hip_bfloat16*)(ws + 51380224);  // overlay (post-G3)
    float*          part = (float*)(ws + 77070336);           // overlay (post-G3)
    __hip_bfloat16* Abf  = (__hip_bfloat16*)(ws + 110100480);
    __hip_bfloat16* Xbf  = (__hip_bfloat16*)(ws + 111706112);

    // 1) frag-convert x and a (one kernel)
    prepXA<<<840, 256, 0, stream>>>(x, a, Xbf, Abf);

    // 2) G1: Ypart[z][b][n] = partial sum_m Xbf[b][m]*Abf[n][m]
    //    waves 16x14 per slice, split-K=4 (7 iters) -> 56 blocks x 4 z
    gemm_fd<0><<<dim3(56, KS_G1), 256, 0, stream>>>(
        Xbf, Abf, 28, 28, 16, 7, 7, (size_t)BATCH * NPAD, Ypart, NPAD, nullptr, nullptr);

    // 3) layer-1 pointwise + @W2 -> Tt frag
    layer1_fuse<<<dim3(NPAD / 128, BATCH), 128, 0, stream>>>(Ypart, w1, b1, w2, Tt);

    // 4) G3: h2 = elu(A @ T + b2), output in h2f frag layout
    //    waves 14 x 512 = 7168 -> 1792 blocks, 28 iters
    gemm_fd<1><<<dim3(1792, 1), 256, 0, stream>>>(
        Abf, Tt, 28, 28, 14, 28, 0, 0, nullptr, 0, h2f, b2);

    // 5) frag-convert wf1 (into dead-Tt region)
    prepW<<<6272, 256, 0, stream>>>(wf1, Wt);

    // 6) G4: fc1 partials, waves 16x8 per slice, split-K=14 (56 iters)
    gemm_fd<2><<<dim3(32, KS_FC), 256, 0, stream>>>(
        h2f, Wt, 784, 784, 16, 56, 56, (size_t)BATCH * HDIM, part, HDIM, nullptr, nullptr);

    // 7) fc1 reduce + relu + fc2 + softmax
    fc2_softmax<<<BATCH / 4, 256, 0, stream>>>(part, bf1, wf2, bf2, out);
}